// Round 1
// baseline (159.032 us; speedup 1.0000x reference)
//
#include <hip/hip_runtime.h>
#include <math.h>

constexpr int NB = 8192;   // batch
constexpr int ND = 1024;   // dim
constexpr int NK = 30;     // negatives

// ---------------------------------------------------------------------------
// Kernel 1: inverse L2 norms for the virtual pool [2B, D]
// rows 0..B-1 = z_i, rows B..2B-1 = z_j. One wave (64 lanes) per row.
// ---------------------------------------------------------------------------
__global__ void norms_kernel(const float* __restrict__ zi,
                             const float* __restrict__ zj,
                             float* __restrict__ inv_norm) {
    int row  = blockIdx.x * 4 + (threadIdx.x >> 6);   // 4 waves / block
    int lane = threadIdx.x & 63;
    if (row >= 2 * NB) return;
    const float* src = (row < NB) ? (zi + (size_t)row * ND)
                                  : (zj + (size_t)(row - NB) * ND);
    float s = 0.f;
#pragma unroll
    for (int seg = 0; seg < 4; ++seg) {
        float4 v = *reinterpret_cast<const float4*>(src + seg * 256 + lane * 4);
        s += v.x * v.x + v.y * v.y + v.z * v.z + v.w * v.w;
    }
#pragma unroll
    for (int off = 32; off >= 1; off >>= 1)
        s += __shfl_xor(s, off, 64);
    if (lane == 0) {
        float n = sqrtf(s);
        inv_norm[row] = 1.f / fmaxf(n, 1e-12f);
    }
}

// ---------------------------------------------------------------------------
// Kernel 2: per-row loss. One wave per row b:
//   logits = [pos_sim, neg_sim_0..29] / T, loss_b = LSE(logits) - logits[0]
// Normalization folded in via inv_norm. Online logsumexp, redundant per lane.
// ---------------------------------------------------------------------------
__global__ void loss_kernel(const float* __restrict__ zi,
                            const float* __restrict__ zj,
                            const int*   __restrict__ neg_idx,
                            const float* __restrict__ temp_ptr,
                            const float* __restrict__ inv_norm,
                            float* __restrict__ partial) {
    int wave = threadIdx.x >> 6;
    int lane = threadIdx.x & 63;
    int row  = blockIdx.x * 4 + wave;

    float inv_t = 1.f / temp_ptr[0];
    const float* a = zi + (size_t)row * ND;

    float4 av[4];
#pragma unroll
    for (int seg = 0; seg < 4; ++seg)
        av[seg] = *reinterpret_cast<const float4*>(a + seg * 256 + lane * 4);

    float inv_a = inv_norm[row];

    float m = -INFINITY, ssum = 0.f, logit0 = 0.f;

    for (int k = -1; k < NK; ++k) {
        int r = (k < 0) ? (row + NB) : neg_idx[row * NK + k];
        const float* bp = (r < NB) ? (zi + (size_t)r * ND)
                                   : (zj + (size_t)(r - NB) * ND);
        float inv_b = inv_norm[r];
        float dot = 0.f;
#pragma unroll
        for (int seg = 0; seg < 4; ++seg) {
            float4 bv = *reinterpret_cast<const float4*>(bp + seg * 256 + lane * 4);
            dot += av[seg].x * bv.x + av[seg].y * bv.y
                 + av[seg].z * bv.z + av[seg].w * bv.w;
        }
#pragma unroll
        for (int off = 32; off >= 1; off >>= 1)
            dot += __shfl_xor(dot, off, 64);
        float logit = dot * inv_a * inv_b * inv_t;
        if (k < 0) logit0 = logit;
        // online logsumexp (all lanes hold the same dot after butterfly)
        if (logit > m) { ssum = ssum * __expf(m - logit) + 1.f; m = logit; }
        else           { ssum += __expf(logit - m); }
    }
    float loss = (m + logf(ssum)) - logit0;

    __shared__ float red[4];
    if (lane == 0) red[wave] = loss;
    __syncthreads();
    if (threadIdx.x == 0)
        partial[blockIdx.x] = red[0] + red[1] + red[2] + red[3];
}

// ---------------------------------------------------------------------------
// Kernel 3: final reduction of per-block partials -> mean loss
// ---------------------------------------------------------------------------
__global__ void reduce_kernel(const float* __restrict__ partial, int n,
                              float* __restrict__ out) {
    float s = 0.f;
    for (int i = threadIdx.x; i < n; i += 256) s += partial[i];
#pragma unroll
    for (int off = 32; off >= 1; off >>= 1)
        s += __shfl_xor(s, off, 64);
    __shared__ float lds[4];
    int wave = threadIdx.x >> 6, lane = threadIdx.x & 63;
    if (lane == 0) lds[wave] = s;
    __syncthreads();
    if (threadIdx.x == 0)
        out[0] = (lds[0] + lds[1] + lds[2] + lds[3]) * (1.f / (float)NB);
}

extern "C" void kernel_launch(void* const* d_in, const int* in_sizes, int n_in,
                              void* d_out, int out_size, void* d_ws, size_t ws_size,
                              hipStream_t stream) {
    const float* zi      = (const float*)d_in[0];
    const float* zj      = (const float*)d_in[1];
    const float* temp    = (const float*)d_in[2];
    const int*   neg_idx = (const int*)d_in[3];
    float* out = (float*)d_out;

    float* inv_norm = (float*)d_ws;                 // 2B floats
    float* partial  = inv_norm + 2 * NB;            // B/4 floats

    // 1 wave per row, 4 waves (256 threads) per block
    norms_kernel<<<(2 * NB) / 4, 256, 0, stream>>>(zi, zj, inv_norm);
    loss_kernel<<<NB / 4, 256, 0, stream>>>(zi, zj, neg_idx, temp, inv_norm, partial);
    reduce_kernel<<<1, 256, 0, stream>>>(partial, NB / 4, out);
}

// Round 2
// 90.321 us; speedup vs baseline: 1.7607x; 1.7607x over previous
//
#include <hip/hip_runtime.h>
#include <hip/hip_fp16.h>
#include <math.h>

constexpr int NB = 8192;   // batch
constexpr int ND = 1024;   // dim
constexpr int NK = 30;     // negatives

struct H4 { __half2 a, b; };   // 8-byte packed store of 4 halves

// ---------------------------------------------------------------------------
// Kernel 1: normalize rows of [z_i; z_j] and write fp16 pool [2B, D].
// One wave per row, 4 waves/block.
// ---------------------------------------------------------------------------
__global__ void normalize_kernel(const float* __restrict__ zi,
                                 const float* __restrict__ zj,
                                 __half* __restrict__ pool) {
    int row  = blockIdx.x * 4 + (threadIdx.x >> 6);
    int lane = threadIdx.x & 63;
    const float* src = (row < NB) ? (zi + (size_t)row * ND)
                                  : (zj + (size_t)(row - NB) * ND);
    float4 v[4];
    float s = 0.f;
#pragma unroll
    for (int seg = 0; seg < 4; ++seg) {
        v[seg] = *reinterpret_cast<const float4*>(src + seg * 256 + lane * 4);
        s += v[seg].x * v[seg].x + v[seg].y * v[seg].y
           + v[seg].z * v[seg].z + v[seg].w * v[seg].w;
    }
#pragma unroll
    for (int off = 32; off >= 1; off >>= 1)
        s += __shfl_xor(s, off, 64);
    float inv = 1.f / fmaxf(sqrtf(s), 1e-12f);

    __half* dst = pool + (size_t)row * ND;
#pragma unroll
    for (int seg = 0; seg < 4; ++seg) {
        H4 h;
        h.a = __floats2half2_rn(v[seg].x * inv, v[seg].y * inv);
        h.b = __floats2half2_rn(v[seg].z * inv, v[seg].w * inv);
        *reinterpret_cast<H4*>(dst + seg * 256 + lane * 4) = h;
    }
}

// ---------------------------------------------------------------------------
// Kernel 2: per-row loss from the fp16 normalized pool. One wave per row.
// Per lane: 16 halves of the a-row cached in registers (natural order:
// seg*512 + lane*8 + j). 30 indices prefetched one-per-lane, __shfl broadcast.
// ---------------------------------------------------------------------------
__global__ void loss_kernel(const __half* __restrict__ pool,
                            const int*   __restrict__ neg_idx,
                            const float* __restrict__ temp_ptr,
                            float* __restrict__ partial) {
    int wave = threadIdx.x >> 6;
    int lane = threadIdx.x & 63;
    int row  = blockIdx.x * 4 + wave;

    float inv_t = 1.f / temp_ptr[0];
    const __half* a = pool + (size_t)row * ND;

    float af[16];
#pragma unroll
    for (int seg = 0; seg < 2; ++seg) {
        float4 raw = *reinterpret_cast<const float4*>(a + seg * 512 + lane * 8);
        const __half2* h = reinterpret_cast<const __half2*>(&raw);
#pragma unroll
        for (int j = 0; j < 4; ++j) {
            float2 f = __half22float2(h[j]);
            af[seg * 8 + j * 2]     = f.x;
            af[seg * 8 + j * 2 + 1] = f.y;
        }
    }

    int myidx = (lane < NK) ? neg_idx[row * NK + lane] : 0;

    float m = -INFINITY, ssum = 0.f, logit0 = 0.f;

    for (int k = -1; k < NK; ++k) {
        int r = (k < 0) ? (row + NB) : __shfl(myidx, k, 64);
        const __half* bp = pool + (size_t)r * ND;
        float dot = 0.f;
#pragma unroll
        for (int seg = 0; seg < 2; ++seg) {
            float4 raw = *reinterpret_cast<const float4*>(bp + seg * 512 + lane * 8);
            const __half2* h = reinterpret_cast<const __half2*>(&raw);
#pragma unroll
            for (int j = 0; j < 4; ++j) {
                float2 f = __half22float2(h[j]);
                dot += af[seg * 8 + j * 2]     * f.x
                     + af[seg * 8 + j * 2 + 1] * f.y;
            }
        }
#pragma unroll
        for (int off = 32; off >= 1; off >>= 1)
            dot += __shfl_xor(dot, off, 64);
        float logit = dot * inv_t;
        if (k < 0) logit0 = logit;
        if (logit > m) { ssum = ssum * __expf(m - logit) + 1.f; m = logit; }
        else           { ssum += __expf(logit - m); }
    }
    float loss = (m + logf(ssum)) - logit0;

    __shared__ float red[4];
    if (lane == 0) red[wave] = loss;
    __syncthreads();
    if (threadIdx.x == 0)
        partial[blockIdx.x] = red[0] + red[1] + red[2] + red[3];
}

// ---------------------------------------------------------------------------
// Fallback f32 path (used only if ws_size is too small for the fp16 pool)
// ---------------------------------------------------------------------------
__global__ void norms_kernel(const float* __restrict__ zi,
                             const float* __restrict__ zj,
                             float* __restrict__ inv_norm) {
    int row  = blockIdx.x * 4 + (threadIdx.x >> 6);
    int lane = threadIdx.x & 63;
    if (row >= 2 * NB) return;
    const float* src = (row < NB) ? (zi + (size_t)row * ND)
                                  : (zj + (size_t)(row - NB) * ND);
    float s = 0.f;
#pragma unroll
    for (int seg = 0; seg < 4; ++seg) {
        float4 v = *reinterpret_cast<const float4*>(src + seg * 256 + lane * 4);
        s += v.x * v.x + v.y * v.y + v.z * v.z + v.w * v.w;
    }
#pragma unroll
    for (int off = 32; off >= 1; off >>= 1)
        s += __shfl_xor(s, off, 64);
    if (lane == 0)
        inv_norm[row] = 1.f / fmaxf(sqrtf(s), 1e-12f);
}

__global__ void loss_kernel_f32(const float* __restrict__ zi,
                                const float* __restrict__ zj,
                                const int*   __restrict__ neg_idx,
                                const float* __restrict__ temp_ptr,
                                const float* __restrict__ inv_norm,
                                float* __restrict__ partial) {
    int wave = threadIdx.x >> 6;
    int lane = threadIdx.x & 63;
    int row  = blockIdx.x * 4 + wave;

    float inv_t = 1.f / temp_ptr[0];
    const float* a = zi + (size_t)row * ND;

    float4 av[4];
#pragma unroll
    for (int seg = 0; seg < 4; ++seg)
        av[seg] = *reinterpret_cast<const float4*>(a + seg * 256 + lane * 4);

    float inv_a = inv_norm[row];
    float m = -INFINITY, ssum = 0.f, logit0 = 0.f;

    for (int k = -1; k < NK; ++k) {
        int r = (k < 0) ? (row + NB) : neg_idx[row * NK + k];
        const float* bp = (r < NB) ? (zi + (size_t)r * ND)
                                   : (zj + (size_t)(r - NB) * ND);
        float inv_b = inv_norm[r];
        float dot = 0.f;
#pragma unroll
        for (int seg = 0; seg < 4; ++seg) {
            float4 bv = *reinterpret_cast<const float4*>(bp + seg * 256 + lane * 4);
            dot += av[seg].x * bv.x + av[seg].y * bv.y
                 + av[seg].z * bv.z + av[seg].w * bv.w;
        }
#pragma unroll
        for (int off = 32; off >= 1; off >>= 1)
            dot += __shfl_xor(dot, off, 64);
        float logit = dot * inv_a * inv_b * inv_t;
        if (k < 0) logit0 = logit;
        if (logit > m) { ssum = ssum * __expf(m - logit) + 1.f; m = logit; }
        else           { ssum += __expf(logit - m); }
    }
    float loss = (m + logf(ssum)) - logit0;

    __shared__ float red[4];
    if (lane == 0) red[wave] = loss;
    __syncthreads();
    if (threadIdx.x == 0)
        partial[blockIdx.x] = red[0] + red[1] + red[2] + red[3];
}

// ---------------------------------------------------------------------------
// Kernel 3: final reduction of per-block partials -> mean loss
// ---------------------------------------------------------------------------
__global__ void reduce_kernel(const float* __restrict__ partial, int n,
                              float* __restrict__ out) {
    float s = 0.f;
    for (int i = threadIdx.x; i < n; i += 256) s += partial[i];
#pragma unroll
    for (int off = 32; off >= 1; off >>= 1)
        s += __shfl_xor(s, off, 64);
    __shared__ float lds[4];
    int wave = threadIdx.x >> 6, lane = threadIdx.x & 63;
    if (lane == 0) lds[wave] = s;
    __syncthreads();
    if (threadIdx.x == 0)
        out[0] = (lds[0] + lds[1] + lds[2] + lds[3]) * (1.f / (float)NB);
}

extern "C" void kernel_launch(void* const* d_in, const int* in_sizes, int n_in,
                              void* d_out, int out_size, void* d_ws, size_t ws_size,
                              hipStream_t stream) {
    const float* zi      = (const float*)d_in[0];
    const float* zj      = (const float*)d_in[1];
    const float* temp    = (const float*)d_in[2];
    const int*   neg_idx = (const int*)d_in[3];
    float* out = (float*)d_out;

    const size_t pool_bytes    = (size_t)2 * NB * ND * sizeof(__half); // 32 MiB
    const size_t partial_bytes = (size_t)(NB / 4) * sizeof(float);

    if (ws_size >= pool_bytes + partial_bytes) {
        __half* pool    = (__half*)d_ws;
        float*  partial = (float*)((char*)d_ws + pool_bytes);

        normalize_kernel<<<(2 * NB) / 4, 256, 0, stream>>>(zi, zj, pool);
        loss_kernel<<<NB / 4, 256, 0, stream>>>(pool, neg_idx, temp, partial);
        reduce_kernel<<<1, 256, 0, stream>>>(partial, NB / 4, out);
    } else {
        float* inv_norm = (float*)d_ws;              // 2B floats
        float* partial  = inv_norm + 2 * NB;         // B/4 floats

        norms_kernel<<<(2 * NB) / 4, 256, 0, stream>>>(zi, zj, inv_norm);
        loss_kernel_f32<<<NB / 4, 256, 0, stream>>>(zi, zj, neg_idx, temp,
                                                    inv_norm, partial);
        reduce_kernel<<<1, 256, 0, stream>>>(partial, NB / 4, out);
    }
}

// Round 3
// 55.847 us; speedup vs baseline: 2.8477x; 1.6173x over previous
//
#include <hip/hip_runtime.h>
#include <math.h>

constexpr int NB = 8192;   // batch
constexpr int ND = 1024;   // dim
constexpr int NK = 30;     // negatives

typedef __attribute__((ext_vector_type(2))) float vf2;

__device__ __forceinline__ int pack4_fp8(float a, float b, float c, float d) {
    int t = 0;
    t = __builtin_amdgcn_cvt_pk_fp8_f32(a, b, t, false);
    t = __builtin_amdgcn_cvt_pk_fp8_f32(c, d, t, true);
    return t;
}

// ---------------------------------------------------------------------------
// Kernel 1: normalize rows of [z_i; z_j] -> fp8 e4m3 pool [2B, D] (16 MiB).
// One wave per row; each lane owns 16 contiguous elements (lane*16 .. +15),
// matching the loss kernel's one-int4-per-lane read.
// ---------------------------------------------------------------------------
__global__ void normalize_fp8_kernel(const float* __restrict__ zi,
                                     const float* __restrict__ zj,
                                     int* __restrict__ pool) {
    int row  = blockIdx.x * 4 + (threadIdx.x >> 6);
    int lane = threadIdx.x & 63;
    const float* src = (row < NB) ? (zi + (size_t)row * ND)
                                  : (zj + (size_t)(row - NB) * ND);
    float v[16];
    float s = 0.f;
#pragma unroll
    for (int seg = 0; seg < 4; ++seg) {
        float4 t = *reinterpret_cast<const float4*>(src + lane * 16 + seg * 4);
        v[seg * 4 + 0] = t.x; v[seg * 4 + 1] = t.y;
        v[seg * 4 + 2] = t.z; v[seg * 4 + 3] = t.w;
        s += t.x * t.x + t.y * t.y + t.z * t.z + t.w * t.w;
    }
#pragma unroll
    for (int off = 32; off >= 1; off >>= 1)
        s += __shfl_xor(s, off, 64);
    float inv = 1.f / fmaxf(sqrtf(s), 1e-12f);

    int4 w;
    w.x = pack4_fp8(v[0] * inv,  v[1] * inv,  v[2] * inv,  v[3] * inv);
    w.y = pack4_fp8(v[4] * inv,  v[5] * inv,  v[6] * inv,  v[7] * inv);
    w.z = pack4_fp8(v[8] * inv,  v[9] * inv,  v[10] * inv, v[11] * inv);
    w.w = pack4_fp8(v[12] * inv, v[13] * inv, v[14] * inv, v[15] * inv);
    *reinterpret_cast<int4*>(pool + row * (ND / 4) + lane * 4) = w;
}

// ---------------------------------------------------------------------------
// Kernel 2: per-row loss from the fp8 pool. One wave per row.
// Row = 1 KiB = exactly one int4 per lane. k-loop chunked by 4 with batched
// loads so >=4 gathers are in flight per wave.
// ---------------------------------------------------------------------------
__global__ void loss_kernel(const int* __restrict__ pool,
                            const int* __restrict__ neg_idx,
                            const float* __restrict__ temp_ptr,
                            float* __restrict__ partial) {
    int wave = threadIdx.x >> 6;
    int lane = threadIdx.x & 63;
    int row  = blockIdx.x * 4 + wave;

    float inv_t = 1.f / temp_ptr[0];

    // a-row (quantized, normalized) -> 16 floats in registers
    float af[16];
    {
        int4 araw = *reinterpret_cast<const int4*>(pool + row * 256 + lane * 4);
        const int* ap = reinterpret_cast<const int*>(&araw);
#pragma unroll
        for (int d = 0; d < 4; ++d) {
            vf2 lo = __builtin_amdgcn_cvt_pk_f32_fp8(ap[d], false);
            vf2 hi = __builtin_amdgcn_cvt_pk_f32_fp8(ap[d], true);
            af[d * 4 + 0] = lo[0]; af[d * 4 + 1] = lo[1];
            af[d * 4 + 2] = hi[0]; af[d * 4 + 3] = hi[1];
        }
    }

    int myidx = (lane < NK) ? neg_idx[row * NK + lane] : 0;

    float m = -INFINITY, ssum = 0.f, logit0 = 0.f;

    // k = 0 is the positive (row+NB), k = 1..30 are negatives.
#pragma unroll
    for (int kc = 0; kc < 31; kc += 4) {
        int4 raw[4];
#pragma unroll
        for (int j = 0; j < 4; ++j) {
            int kk = kc + j;
            if (kk < 31) {
                int r = (kk == 0) ? (row + NB) : __shfl(myidx, kk - 1, 64);
                raw[j] = *reinterpret_cast<const int4*>(pool + r * 256 + lane * 4);
            }
        }
#pragma unroll
        for (int j = 0; j < 4; ++j) {
            int kk = kc + j;
            if (kk < 31) {
                const int* rp = reinterpret_cast<const int*>(&raw[j]);
                float dot = 0.f;
#pragma unroll
                for (int d = 0; d < 4; ++d) {
                    vf2 lo = __builtin_amdgcn_cvt_pk_f32_fp8(rp[d], false);
                    vf2 hi = __builtin_amdgcn_cvt_pk_f32_fp8(rp[d], true);
                    dot += af[d * 4 + 0] * lo[0] + af[d * 4 + 1] * lo[1]
                         + af[d * 4 + 2] * hi[0] + af[d * 4 + 3] * hi[1];
                }
#pragma unroll
                for (int off = 32; off >= 1; off >>= 1)
                    dot += __shfl_xor(dot, off, 64);
                float logit = dot * inv_t;
                if (kk == 0) {
                    logit0 = logit; m = logit; ssum = 1.f;
                } else {
                    float nm = fmaxf(m, logit);
                    ssum = ssum * __expf(m - nm) + __expf(logit - nm);
                    m = nm;
                }
            }
        }
    }
    float loss = (m + logf(ssum)) - logit0;

    __shared__ float red[4];
    if (lane == 0) red[wave] = loss;
    __syncthreads();
    if (threadIdx.x == 0)
        partial[blockIdx.x] = red[0] + red[1] + red[2] + red[3];
}

// ---------------------------------------------------------------------------
// Fallback f32 path (only if ws_size is too small for the fp8 pool)
// ---------------------------------------------------------------------------
__global__ void norms_kernel(const float* __restrict__ zi,
                             const float* __restrict__ zj,
                             float* __restrict__ inv_norm) {
    int row  = blockIdx.x * 4 + (threadIdx.x >> 6);
    int lane = threadIdx.x & 63;
    if (row >= 2 * NB) return;
    const float* src = (row < NB) ? (zi + (size_t)row * ND)
                                  : (zj + (size_t)(row - NB) * ND);
    float s = 0.f;
#pragma unroll
    for (int seg = 0; seg < 4; ++seg) {
        float4 v = *reinterpret_cast<const float4*>(src + seg * 256 + lane * 4);
        s += v.x * v.x + v.y * v.y + v.z * v.z + v.w * v.w;
    }
#pragma unroll
    for (int off = 32; off >= 1; off >>= 1)
        s += __shfl_xor(s, off, 64);
    if (lane == 0)
        inv_norm[row] = 1.f / fmaxf(sqrtf(s), 1e-12f);
}

__global__ void loss_kernel_f32(const float* __restrict__ zi,
                                const float* __restrict__ zj,
                                const int*   __restrict__ neg_idx,
                                const float* __restrict__ temp_ptr,
                                const float* __restrict__ inv_norm,
                                float* __restrict__ partial) {
    int wave = threadIdx.x >> 6;
    int lane = threadIdx.x & 63;
    int row  = blockIdx.x * 4 + wave;

    float inv_t = 1.f / temp_ptr[0];
    const float* a = zi + (size_t)row * ND;

    float4 av[4];
#pragma unroll
    for (int seg = 0; seg < 4; ++seg)
        av[seg] = *reinterpret_cast<const float4*>(a + seg * 256 + lane * 4);

    float inv_a = inv_norm[row];
    float m = -INFINITY, ssum = 0.f, logit0 = 0.f;

    for (int k = -1; k < NK; ++k) {
        int r = (k < 0) ? (row + NB) : neg_idx[row * NK + k];
        const float* bp = (r < NB) ? (zi + (size_t)r * ND)
                                   : (zj + (size_t)(r - NB) * ND);
        float inv_b = inv_norm[r];
        float dot = 0.f;
#pragma unroll
        for (int seg = 0; seg < 4; ++seg) {
            float4 bv = *reinterpret_cast<const float4*>(bp + seg * 256 + lane * 4);
            dot += av[seg].x * bv.x + av[seg].y * bv.y
                 + av[seg].z * bv.z + av[seg].w * bv.w;
        }
#pragma unroll
        for (int off = 32; off >= 1; off >>= 1)
            dot += __shfl_xor(dot, off, 64);
        float logit = dot * inv_a * inv_b * inv_t;
        if (k < 0) logit0 = logit;
        if (logit > m) { ssum = ssum * __expf(m - logit) + 1.f; m = logit; }
        else           { ssum += __expf(logit - m); }
    }
    float loss = (m + logf(ssum)) - logit0;

    __shared__ float red[4];
    if (lane == 0) red[wave] = loss;
    __syncthreads();
    if (threadIdx.x == 0)
        partial[blockIdx.x] = red[0] + red[1] + red[2] + red[3];
}

// ---------------------------------------------------------------------------
// Kernel 3: final reduction of per-block partials -> mean loss
// ---------------------------------------------------------------------------
__global__ void reduce_kernel(const float* __restrict__ partial, int n,
                              float* __restrict__ out) {
    float s = 0.f;
    for (int i = threadIdx.x; i < n; i += 256) s += partial[i];
#pragma unroll
    for (int off = 32; off >= 1; off >>= 1)
        s += __shfl_xor(s, off, 64);
    __shared__ float lds[4];
    int wave = threadIdx.x >> 6, lane = threadIdx.x & 63;
    if (lane == 0) lds[wave] = s;
    __syncthreads();
    if (threadIdx.x == 0)
        out[0] = (lds[0] + lds[1] + lds[2] + lds[3]) * (1.f / (float)NB);
}

extern "C" void kernel_launch(void* const* d_in, const int* in_sizes, int n_in,
                              void* d_out, int out_size, void* d_ws, size_t ws_size,
                              hipStream_t stream) {
    const float* zi      = (const float*)d_in[0];
    const float* zj      = (const float*)d_in[1];
    const float* temp    = (const float*)d_in[2];
    const int*   neg_idx = (const int*)d_in[3];
    float* out = (float*)d_out;

    const size_t pool_bytes    = (size_t)2 * NB * ND;            // fp8: 16 MiB
    const size_t partial_bytes = (size_t)(NB / 4) * sizeof(float);

    if (ws_size >= pool_bytes + partial_bytes) {
        int*   pool    = (int*)d_ws;
        float* partial = (float*)((char*)d_ws + pool_bytes);

        normalize_fp8_kernel<<<(2 * NB) / 4, 256, 0, stream>>>(zi, zj, pool);
        loss_kernel<<<NB / 4, 256, 0, stream>>>(pool, neg_idx, temp, partial);
        reduce_kernel<<<1, 256, 0, stream>>>(partial, NB / 4, out);
    } else {
        float* inv_norm = (float*)d_ws;              // 2B floats
        float* partial  = inv_norm + 2 * NB;         // B/4 floats

        norms_kernel<<<(2 * NB) / 4, 256, 0, stream>>>(zi, zj, inv_norm);
        loss_kernel_f32<<<NB / 4, 256, 0, stream>>>(zi, zj, neg_idx, temp,
                                                    inv_norm, partial);
        reduce_kernel<<<1, 256, 0, stream>>>(partial, NB / 4, out);
    }
}